// Round 1
// baseline (327.290 us; speedup 1.0000x reference)
//
#include <hip/hip_runtime.h>
#include <math.h>

#define BATCH 1024
#define NV 5023
#define NJ 5
#define K1 150
#define K2 36
#define KTOT 186
#define MCOLS (NV*3)        // 15069
#define NCHUNK 40
#define CHUNKV 126          // ceil(5023/40)

// ws layout (float offsets)
#define WS_PARTIAL 0
#define WS_JSD     (NCHUNK*NJ*453)            // 90600
#define WS_AMAT    (WS_JSD + NJ*453)          // 92865
#define WS_RELTF   (WS_AMAT + BATCH*KTOT)     // 283329
#define WS_Y       (WS_RELTF + BATCH*60)      // 344769
// total 345793 floats ~= 1.38 MB

__device__ __forceinline__ void rodrigues(const float* rv, float* R) {
  // angle = ||rv + 1e-8|| (elementwise offset, per reference), n = rv/angle
  const float ex = rv[0]+1e-8f, ey = rv[1]+1e-8f, ez = rv[2]+1e-8f;
  const float angle = sqrtf(ex*ex + ey*ey + ez*ez);
  const float inv = 1.0f/angle;
  const float nx = rv[0]*inv, ny = rv[1]*inv, nz = rv[2]*inv;
  const float s = sinf(angle), c = cosf(angle);
  const float omc = 1.0f - c;
  R[0] = 1.0f - omc*(ny*ny+nz*nz);
  R[1] = -s*nz + omc*nx*ny;
  R[2] =  s*ny + omc*nx*nz;
  R[3] =  s*nz + omc*nx*ny;
  R[4] = 1.0f - omc*(nx*nx+nz*nz);
  R[5] = -s*nx + omc*ny*nz;
  R[6] = -s*ny + omc*nx*nz;
  R[7] =  s*nx + omc*ny*nz;
  R[8] = 1.0f - omc*(nx*nx+ny*ny);
}

// ---- k1: partial reduction of J_regressor over V, folded into shapedirs + template
__launch_bounds__(512)
__global__ void k1_jsd_partial(const float* __restrict__ jreg, const float* __restrict__ shdirs,
                               const float* __restrict__ vtemp, float* __restrict__ partial) {
  const int j = blockIdx.x;        // 0..4
  const int chunk = blockIdx.y;    // 0..39
  const int t = threadIdx.x;       // 512, 453 active
  if (t >= 453) return;
  const int v0 = chunk*CHUNKV;
  const int v1 = (v0 + CHUNKV < NV) ? v0 + CHUNKV : NV;
  float acc = 0.0f;
  if (t < 450) {
    for (int v = v0; v < v1; ++v)
      acc = fmaf(jreg[j*NV + v], shdirs[(size_t)v*450 + t], acc);
  } else {
    const int c = t - 450;
    for (int v = v0; v < v1; ++v)
      acc = fmaf(jreg[j*NV + v], vtemp[v*3 + c], acc);
  }
  partial[(size_t)(chunk*NJ + j)*453 + t] = acc;
}

__launch_bounds__(256)
__global__ void k1b_jsd_reduce(const float* __restrict__ partial, float* __restrict__ jsd) {
  const int i = blockIdx.x*256 + threadIdx.x;   // 0..2264
  if (i >= NJ*453) return;
  float s = 0.0f;
  for (int c = 0; c < NCHUNK; ++c) s += partial[(size_t)c*(NJ*453) + i];
  jsd[i] = s;
}

// ---- k2: per-batch pose pipeline
__launch_bounds__(256)
__global__ void k2_pose(const float* __restrict__ shape, const float* __restrict__ expr,
                        const float* __restrict__ pose, const float* __restrict__ neck,
                        const float* __restrict__ eye, const float* __restrict__ jsd,
                        float* __restrict__ Amat, float* __restrict__ reltf, int* __restrict__ yidx) {
  const int b = blockIdx.x*256 + threadIdx.x;
  if (b >= BATCH) return;

  float fp[15];
  fp[0]=pose[b*6+0]; fp[1]=pose[b*6+1]; fp[2]=pose[b*6+2];
  fp[3]=neck[0];     fp[4]=neck[1];     fp[5]=neck[2];
  fp[6]=pose[b*6+3]; fp[7]=pose[b*6+4]; fp[8]=pose[b*6+5];
  #pragma unroll
  for (int i=0;i<6;++i) fp[9+i] = eye[i];

  float R[5][9];
  #pragma unroll
  for (int j=0;j<5;++j) rodrigues(&fp[j*3], R[j]);

  // A matrix row: [betas(150) | pose_feature(36)]
  float* Ab = Amat + (size_t)b*KTOT;
  for (int l=0;l<100;++l) Ab[l] = shape[(size_t)b*100 + l];
  for (int l=0;l<50;++l)  Ab[100+l] = expr[(size_t)b*50 + l];
  #pragma unroll
  for (int jj=0;jj<4;++jj)
    #pragma unroll
    for (int rc=0;rc<9;++rc)
      Ab[150 + jj*9 + rc] = R[1+jj][rc] - ((rc==0||rc==4||rc==8)?1.0f:0.0f);

  // joints[j][c] = Jt + Jsd . betas
  float jac[15];
  #pragma unroll
  for (int jc=0;jc<15;++jc) jac[jc] = jsd[(jc/3)*453 + 450 + (jc%3)];
  for (int l=0;l<150;++l) {
    const float bv = (l<100) ? shape[(size_t)b*100+l] : expr[(size_t)b*50 + (l-100)];
    #pragma unroll
    for (int jc=0;jc<15;++jc)
      jac[jc] = fmaf(jsd[(jc/3)*453 + (jc%3)*150 + l], bv, jac[jc]);
  }

  // kinematic chain (3x4 rows, implicit bottom row [0,0,0,1])
  float C[5][12];
  #pragma unroll
  for (int r=0;r<3;++r) {
    C[0][r*4+0]=R[0][r*3+0]; C[0][r*4+1]=R[0][r*3+1]; C[0][r*4+2]=R[0][r*3+2];
    C[0][r*4+3]=jac[r];
  }
  const int par[5] = {-1,0,1,1,1};
  #pragma unroll
  for (int i=1;i<5;++i) {
    const int p = par[i];
    const float rj0 = jac[i*3+0]-jac[p*3+0];
    const float rj1 = jac[i*3+1]-jac[p*3+1];
    const float rj2 = jac[i*3+2]-jac[p*3+2];
    #pragma unroll
    for (int r=0;r<3;++r) {
      const float c0=C[p][r*4+0], c1=C[p][r*4+1], c2=C[p][r*4+2], c3=C[p][r*4+3];
      C[i][r*4+0] = c0*R[i][0] + c1*R[i][3] + c2*R[i][6];
      C[i][r*4+1] = c0*R[i][1] + c1*R[i][4] + c2*R[i][7];
      C[i][r*4+2] = c0*R[i][2] + c1*R[i][5] + c2*R[i][8];
      C[i][r*4+3] = c0*rj0 + c1*rj1 + c2*rj2 + c3;
    }
  }

  // rel_tf = chain with translation t - R.j
  float* rt = reltf + (size_t)b*60;
  #pragma unroll
  for (int j=0;j<5;++j) {
    const float jx=jac[j*3+0], jy=jac[j*3+1], jz=jac[j*3+2];
    #pragma unroll
    for (int r=0;r<3;++r) {
      const float m0=C[j][r*4+0], m1=C[j][r*4+1], m2=C[j][r*4+2], m3=C[j][r*4+3];
      rt[j*12+r*4+0]=m0; rt[j*12+r*4+1]=m1; rt[j*12+r*4+2]=m2;
      rt[j*12+r*4+3]=m3 - (m0*jx + m1*jy + m2*jz);
    }
  }

  // neck-chain dynamic landmark index: rel_rot = R(joint0) @ R(joint1), need col 0
  const float c00=R[1][0], c10=R[1][3], c20=R[1][6];
  const float r00 = R[0][0]*c00 + R[0][1]*c10 + R[0][2]*c20;
  const float r10 = R[0][3]*c00 + R[0][4]*c10 + R[0][5]*c20;
  const float r20 = R[0][6]*c00 + R[0][7]*c10 + R[0][8]*c20;
  const float sy = sqrtf(r00*r00 + r10*r10);
  const float yang = atan2f(-r20, sy) * 57.29577951308232f;
  int y = (int)rintf(fminf(yang, 39.0f));
  if (y < 0) y = (y < -39) ? 78 : (39 - y);
  yidx[b] = y;
}

// ---- k3: fused v_shaped + v_posed + LBS  (32 batches x 64 vertices per block)
#define TV 64
#define TB 32
__launch_bounds__(256)
__global__ void k3_vertices(const float* __restrict__ Amat, const float* __restrict__ shdirs,
                            const float* __restrict__ pdirs, const float* __restrict__ vtemp,
                            const float* __restrict__ lbsw, const float* __restrict__ reltf,
                            float* __restrict__ vout) {
  __shared__ float shB[TV*3][37];   // K-chunk of shapedirs/posedirs rows
  __shared__ float shA[TB][37];     // K-chunk of A-matrix
  __shared__ float sRel[TB][60];    // rel_tf per batch

  const int t = threadIdx.x;
  const int v0 = blockIdx.x * TV;
  const int b0 = blockIdx.y * TB;
  const int m0 = v0*3;
  const int vl = t & 63;
  const int bg = t >> 6;            // 0..3 (8 batches each)

  float acc[8][3];
  #pragma unroll
  for (int i=0;i<8;++i) { acc[i][0]=0.f; acc[i][1]=0.f; acc[i][2]=0.f; }

  for (int i=t; i<TB*60; i+=256)
    sRel[i/60][i%60] = reltf[(size_t)(b0 + i/60)*60 + (i%60)];

  // phase 1: shapedirs, K=150 in chunks of 32
  for (int k0=0; k0<K1; k0+=32) {
    const int kl = (K1-k0 < 32) ? (K1-k0) : 32;
    __syncthreads();
    for (int i=t; i<TB*kl; i+=256) {
      const int bl=i/kl, kk=i-bl*kl;
      shA[bl][kk] = Amat[(size_t)(b0+bl)*KTOT + k0+kk];
    }
    for (int i=t; i<TV*3*kl; i+=256) {
      const int r=i/kl, kk=i-r*kl;
      int m = m0 + r; if (m > MCOLS-1) m = MCOLS-1;
      shB[r][kk] = shdirs[(size_t)m*K1 + k0+kk];
    }
    __syncthreads();
    for (int kk=0; kk<kl; ++kk) {
      const float s0 = shB[vl*3+0][kk], s1 = shB[vl*3+1][kk], s2 = shB[vl*3+2][kk];
      #pragma unroll
      for (int i=0;i<8;++i) {
        const float a = shA[bg*8+i][kk];
        acc[i][0] = fmaf(a, s0, acc[i][0]);
        acc[i][1] = fmaf(a, s1, acc[i][1]);
        acc[i][2] = fmaf(a, s2, acc[i][2]);
      }
    }
  }
  // phase 2: posedirs, K=36
  {
    __syncthreads();
    for (int i=t; i<TB*K2; i+=256) {
      const int bl=i/K2, kk=i-bl*K2;
      shA[bl][kk] = Amat[(size_t)(b0+bl)*KTOT + K1+kk];
    }
    for (int i=t; i<TV*3*K2; i+=256) {
      const int k=i/(TV*3), r=i-k*(TV*3);
      int m = m0 + r; if (m > MCOLS-1) m = MCOLS-1;
      shB[r][k] = pdirs[(size_t)k*MCOLS + m];
    }
    __syncthreads();
    for (int kk=0; kk<K2; ++kk) {
      const float s0 = shB[vl*3+0][kk], s1 = shB[vl*3+1][kk], s2 = shB[vl*3+2][kk];
      #pragma unroll
      for (int i=0;i<8;++i) {
        const float a = shA[bg*8+i][kk];
        acc[i][0] = fmaf(a, s0, acc[i][0]);
        acc[i][1] = fmaf(a, s1, acc[i][1]);
        acc[i][2] = fmaf(a, s2, acc[i][2]);
      }
    }
  }

  // epilogue: add template, LBS blend, store
  const int v = v0 + vl;
  if (v < NV) {
    float w[5];
    #pragma unroll
    for (int j=0;j<5;++j) w[j] = lbsw[(size_t)v*5 + j];
    const float tx = vtemp[(size_t)v*3+0], ty = vtemp[(size_t)v*3+1], tz = vtemp[(size_t)v*3+2];
    #pragma unroll
    for (int i=0;i<8;++i) {
      const int bl = bg*8+i;
      const float vx = acc[i][0]+tx, vy = acc[i][1]+ty, vz = acc[i][2]+tz;
      float o[3];
      #pragma unroll
      for (int r=0;r<3;++r) {
        float a0=0.f,a1=0.f,a2=0.f,a3=0.f;
        #pragma unroll
        for (int j=0;j<5;++j) {
          const float* p = &sRel[bl][j*12 + r*4];
          a0 = fmaf(w[j], p[0], a0);
          a1 = fmaf(w[j], p[1], a1);
          a2 = fmaf(w[j], p[2], a2);
          a3 = fmaf(w[j], p[3], a3);
        }
        o[r] = fmaf(a0, vx, fmaf(a1, vy, fmaf(a2, vz, a3)));
      }
      float* dst = vout + ((size_t)(b0+bl)*NV + v)*3;
      dst[0]=o[0]; dst[1]=o[1]; dst[2]=o[2];
    }
  }
}

// ---- k4: landmarks (2d: 17 dynamic + 51 static; 3d: 68 static)
__launch_bounds__(192)
__global__ void k4_landmarks(const float* __restrict__ verts, const int* __restrict__ faces,
                             const int* __restrict__ lmkf, const float* __restrict__ lmkb,
                             const int* __restrict__ dynf, const float* __restrict__ dynb,
                             const int* __restrict__ fullf, const float* __restrict__ fullb,
                             const int* __restrict__ yidx, float* __restrict__ out2d,
                             float* __restrict__ out3d) {
  const int b = blockIdx.x;
  const int t = threadIdx.x;
  if (t >= 136) return;
  const int which = t >= 68;          // 0 -> 2d, 1 -> 3d
  const int i = which ? (t-68) : t;
  int fidx; float bw0,bw1,bw2;
  if (!which) {
    if (i < 17) {
      const int y = yidx[b];
      fidx = dynf[y*17 + i];
      const float* p = dynb + ((size_t)y*17 + i)*3;
      bw0=p[0]; bw1=p[1]; bw2=p[2];
    } else {
      fidx = lmkf[i-17];
      const float* p = lmkb + (size_t)(i-17)*3;
      bw0=p[0]; bw1=p[1]; bw2=p[2];
    }
  } else {
    fidx = fullf[i];
    const float* p = fullb + (size_t)i*3;
    bw0=p[0]; bw1=p[1]; bw2=p[2];
  }
  const int t0 = faces[fidx*3+0], t1 = faces[fidx*3+1], t2 = faces[fidx*3+2];
  const float* vb = verts + (size_t)b*NV*3;
  float* dst = (which ? out3d : out2d) + ((size_t)b*68 + i)*3;
  #pragma unroll
  for (int c=0;c<3;++c)
    dst[c] = vb[(size_t)t0*3+c]*bw0 + vb[(size_t)t1*3+c]*bw1 + vb[(size_t)t2*3+c]*bw2;
}

extern "C" void kernel_launch(void* const* d_in, const int* in_sizes, int n_in,
                              void* d_out, int out_size, void* d_ws, size_t ws_size,
                              hipStream_t stream) {
  const float* shape = (const float*)d_in[0];
  const float* expr  = (const float*)d_in[1];
  const float* pose  = (const float*)d_in[2];
  const float* vtemp = (const float*)d_in[3];
  const float* shdirs= (const float*)d_in[4];
  const float* pdirs = (const float*)d_in[5];
  const float* jreg  = (const float*)d_in[6];
  const float* lbsw  = (const float*)d_in[7];
  const float* neck  = (const float*)d_in[8];
  const float* eye   = (const float*)d_in[9];
  const int*   faces = (const int*)d_in[10];
  const int*   lmkf  = (const int*)d_in[11];
  const float* lmkb  = (const float*)d_in[12];
  const int*   dynf  = (const int*)d_in[13];
  const float* dynb  = (const float*)d_in[14];
  const int*   fullf = (const int*)d_in[15];
  const float* fullb = (const float*)d_in[16];

  float* wsf = (float*)d_ws;
  float* partial = wsf + WS_PARTIAL;
  float* jsd     = wsf + WS_JSD;
  float* Amat    = wsf + WS_AMAT;
  float* reltf   = wsf + WS_RELTF;
  int*   yidx    = (int*)(wsf + WS_Y);

  float* vout  = (float*)d_out;
  float* out2d = vout + (size_t)BATCH*NV*3;
  float* out3d = out2d + (size_t)BATCH*68*3;

  hipLaunchKernelGGL(k1_jsd_partial, dim3(NJ, NCHUNK), dim3(512), 0, stream,
                     jreg, shdirs, vtemp, partial);
  hipLaunchKernelGGL(k1b_jsd_reduce, dim3(9), dim3(256), 0, stream, partial, jsd);
  hipLaunchKernelGGL(k2_pose, dim3(4), dim3(256), 0, stream,
                     shape, expr, pose, neck, eye, jsd, Amat, reltf, yidx);
  hipLaunchKernelGGL(k3_vertices, dim3((NV+TV-1)/TV, BATCH/TB), dim3(256), 0, stream,
                     Amat, shdirs, pdirs, vtemp, lbsw, reltf, vout);
  hipLaunchKernelGGL(k4_landmarks, dim3(BATCH), dim3(192), 0, stream,
                     vout, faces, lmkf, lmkb, dynf, dynb, fullf, fullb, yidx, out2d, out3d);
}

// Round 4
// 268.358 us; speedup vs baseline: 1.2196x; 1.2196x over previous
//
#include <hip/hip_runtime.h>
#include <math.h>

#define BATCH 1024
#define NV 5023
#define NJ 5
#define K1 150
#define K2 36
#define KTOT 186
#define MCOLS (NV*3)        // 15069
#define NCHUNK 40
#define CHUNKV 126

// ws layout (float offsets) — identical to round 1 (proven ws_size >= 1.38 MB)
#define WS_PARTIAL 0
#define WS_JSD     (NCHUNK*NJ*453)            // 90600
#define WS_AMAT    (WS_JSD + NJ*453)          // 92865
#define WS_RELTF   (WS_AMAT + BATCH*KTOT)     // 283329
#define WS_Y       (WS_RELTF + BATCH*60)      // 344769

__device__ __forceinline__ void rodrigues(const float* rv, float* R) {
  const float ex = rv[0]+1e-8f, ey = rv[1]+1e-8f, ez = rv[2]+1e-8f;
  const float angle = sqrtf(ex*ex + ey*ey + ez*ez);
  const float inv = 1.0f/angle;
  const float nx = rv[0]*inv, ny = rv[1]*inv, nz = rv[2]*inv;
  const float s = sinf(angle), c = cosf(angle);
  const float omc = 1.0f - c;
  R[0] = 1.0f - omc*(ny*ny+nz*nz);
  R[1] = -s*nz + omc*nx*ny;
  R[2] =  s*ny + omc*nx*nz;
  R[3] =  s*nz + omc*nx*ny;
  R[4] = 1.0f - omc*(nx*nx+nz*nz);
  R[5] = -s*nx + omc*ny*nz;
  R[6] = -s*ny + omc*nx*nz;
  R[7] =  s*nx + omc*ny*nz;
  R[8] = 1.0f - omc*(nx*nx+ny*ny);
}

// ---- k1: partial reduction of J_regressor over V, folded into shapedirs + template
__launch_bounds__(512)
__global__ void k1_jsd_partial(const float* __restrict__ jreg, const float* __restrict__ shdirs,
                               const float* __restrict__ vtemp, float* __restrict__ partial) {
  const int j = blockIdx.x;
  const int chunk = blockIdx.y;
  const int t = threadIdx.x;
  if (t >= 453) return;
  const int v0 = chunk*CHUNKV;
  const int v1 = (v0 + CHUNKV < NV) ? v0 + CHUNKV : NV;
  float acc = 0.0f;
  if (t < 450) {
    for (int v = v0; v < v1; ++v)
      acc = fmaf(jreg[j*NV + v], shdirs[(size_t)v*450 + t], acc);
  } else {
    const int c = t - 450;
    for (int v = v0; v < v1; ++v)
      acc = fmaf(jreg[j*NV + v], vtemp[v*3 + c], acc);
  }
  partial[(size_t)(chunk*NJ + j)*453 + t] = acc;
}

__launch_bounds__(256)
__global__ void k1b_jsd_reduce(const float* __restrict__ partial, float* __restrict__ jsd) {
  const int i = blockIdx.x*256 + threadIdx.x;
  if (i >= NJ*453) return;
  float s = 0.0f;
  for (int c = 0; c < NCHUNK; ++c) s += partial[(size_t)c*(NJ*453) + i];
  jsd[i] = s;
}

// ---- k2: per-batch pose pipeline (round-1 version, fp32 Amat) ----
__launch_bounds__(256)
__global__ void k2_pose(const float* __restrict__ shape, const float* __restrict__ expr,
                        const float* __restrict__ pose, const float* __restrict__ neck,
                        const float* __restrict__ eye, const float* __restrict__ jsd,
                        float* __restrict__ Amat, float* __restrict__ reltf, int* __restrict__ yidx) {
  const int b = blockIdx.x*256 + threadIdx.x;
  if (b >= BATCH) return;

  float fp[15];
  fp[0]=pose[b*6+0]; fp[1]=pose[b*6+1]; fp[2]=pose[b*6+2];
  fp[3]=neck[0];     fp[4]=neck[1];     fp[5]=neck[2];
  fp[6]=pose[b*6+3]; fp[7]=pose[b*6+4]; fp[8]=pose[b*6+5];
  #pragma unroll
  for (int i=0;i<6;++i) fp[9+i] = eye[i];

  float R[5][9];
  #pragma unroll
  for (int j=0;j<5;++j) rodrigues(&fp[j*3], R[j]);

  float* Ab = Amat + (size_t)b*KTOT;
  for (int l=0;l<100;++l) Ab[l] = shape[(size_t)b*100 + l];
  for (int l=0;l<50;++l)  Ab[100+l] = expr[(size_t)b*50 + l];
  #pragma unroll
  for (int jj=0;jj<4;++jj)
    #pragma unroll
    for (int rc=0;rc<9;++rc)
      Ab[150 + jj*9 + rc] = R[1+jj][rc] - ((rc==0||rc==4||rc==8)?1.0f:0.0f);

  float jac[15];
  #pragma unroll
  for (int jc=0;jc<15;++jc) jac[jc] = jsd[(jc/3)*453 + 450 + (jc%3)];
  for (int l=0;l<150;++l) {
    const float bv = (l<100) ? shape[(size_t)b*100+l] : expr[(size_t)b*50 + (l-100)];
    #pragma unroll
    for (int jc=0;jc<15;++jc)
      jac[jc] = fmaf(jsd[(jc/3)*453 + (jc%3)*150 + l], bv, jac[jc]);
  }

  float C[5][12];
  #pragma unroll
  for (int r=0;r<3;++r) {
    C[0][r*4+0]=R[0][r*3+0]; C[0][r*4+1]=R[0][r*3+1]; C[0][r*4+2]=R[0][r*3+2];
    C[0][r*4+3]=jac[r];
  }
  const int par[5] = {-1,0,1,1,1};
  #pragma unroll
  for (int i=1;i<5;++i) {
    const int p = par[i];
    const float rj0 = jac[i*3+0]-jac[p*3+0];
    const float rj1 = jac[i*3+1]-jac[p*3+1];
    const float rj2 = jac[i*3+2]-jac[p*3+2];
    #pragma unroll
    for (int r=0;r<3;++r) {
      const float c0=C[p][r*4+0], c1=C[p][r*4+1], c2=C[p][r*4+2], c3=C[p][r*4+3];
      C[i][r*4+0] = c0*R[i][0] + c1*R[i][3] + c2*R[i][6];
      C[i][r*4+1] = c0*R[i][1] + c1*R[i][4] + c2*R[i][7];
      C[i][r*4+2] = c0*R[i][2] + c1*R[i][5] + c2*R[i][8];
      C[i][r*4+3] = c0*rj0 + c1*rj1 + c2*rj2 + c3;
    }
  }

  float* rt = reltf + (size_t)b*60;
  #pragma unroll
  for (int j=0;j<5;++j) {
    const float jx=jac[j*3+0], jy=jac[j*3+1], jz=jac[j*3+2];
    #pragma unroll
    for (int r=0;r<3;++r) {
      const float m0=C[j][r*4+0], m1=C[j][r*4+1], m2=C[j][r*4+2], m3=C[j][r*4+3];
      rt[j*12+r*4+0]=m0; rt[j*12+r*4+1]=m1; rt[j*12+r*4+2]=m2;
      rt[j*12+r*4+3]=m3 - (m0*jx + m1*jy + m2*jz);
    }
  }

  const float c00=R[1][0], c10=R[1][3], c20=R[1][6];
  const float r00 = R[0][0]*c00 + R[0][1]*c10 + R[0][2]*c20;
  const float r10 = R[0][3]*c00 + R[0][4]*c10 + R[0][5]*c20;
  const float r20 = R[0][6]*c00 + R[0][7]*c10 + R[0][8]*c20;
  const float sy = sqrtf(r00*r00 + r10*r10);
  const float yang = atan2f(-r20, sy) * 57.29577951308232f;
  int y = (int)rintf(fminf(yang, 39.0f));
  if (y < 0) y = (y < -39) ? 78 : (39 - y);
  yidx[b] = y;
}

// ---- k3 v2: fused GEMM + LBS. 128 verts x 64 batches, 512 threads.
// thread = (vl in 0..63 -> verts {vl, vl+64}) x (bg in 0..7 -> 8 batches)
#define TV 128
#define TB 64
#define LDSB 33     // padded K-stride for LDS tiles

__launch_bounds__(512, 4)
__global__ void k3_valu(const float* __restrict__ Amat, const float* __restrict__ shdirs,
                        const float* __restrict__ pdirs, const float* __restrict__ vtemp,
                        const float* __restrict__ lbsw, const float* __restrict__ reltf,
                        float* __restrict__ vout) {
  __shared__ float shB[TV*3*LDSB];   // 384 x 33 = 50688 B
  __shared__ float shA[TB*LDSB];     // 64 x 33  = 8448 B
  __shared__ float sRel[TB*60];      // 15360 B

  const int t = threadIdx.x;
  const int vl = t & 63;
  const int bg = t >> 6;             // 0..7
  const int v0 = blockIdx.x * TV;
  const int b0 = blockIdx.y * TB;
  const int m0 = v0*3;

  // stage rel_tf (contiguous copy: (b0+i/60)*60 + i%60 == b0*60 + i)
  for (int i = t; i < TB*60; i += 512)
    sRel[i] = reltf[(size_t)b0*60 + i];

  float acc[2][8][3];
  #pragma unroll
  for (int p=0;p<2;++p)
    #pragma unroll
    for (int i=0;i<8;++i) { acc[p][i][0]=0.f; acc[p][i][1]=0.f; acc[p][i][2]=0.f; }

  // K chunks: shapedirs [0..150) then posedirs [150..186)
  const int k0s[7] = {0, 32, 64, 96, 128, 150, 182};
  const int kls[7] = {32, 32, 32, 32, 22, 32, 4};

  for (int ch = 0; ch < 7; ++ch) {
    const int k0 = k0s[ch], kl = kls[ch];
    __syncthreads();
    // stage A chunk
    for (int i = t; i < TB*kl; i += 512) {
      const int bl = i/kl, kk = i - bl*kl;
      shA[bl*LDSB + kk] = Amat[(size_t)(b0+bl)*KTOT + k0 + kk];
    }
    // stage B chunk
    if (k0 < K1) {
      const int half = kl >> 1;   // kl even for all shapedirs chunks
      for (int i = t; i < TV*3*half; i += 512) {
        const int r = i/half, q = i - r*half;
        int m = m0 + r; if (m > MCOLS-1) m = MCOLS-1;
        const float2 f = *reinterpret_cast<const float2*>(shdirs + (size_t)m*K1 + k0 + q*2);
        shB[r*LDSB + q*2]     = f.x;
        shB[r*LDSB + q*2 + 1] = f.y;
      }
    } else {
      for (int i = t; i < kl*TV*3; i += 512) {
        const int kk = i/(TV*3), r = i - kk*(TV*3);
        int m = m0 + r; if (m > MCOLS-1) m = MCOLS-1;
        shB[r*LDSB + kk] = pdirs[(size_t)(k0 - K1 + kk)*MCOLS + m];
      }
    }
    __syncthreads();

    for (int kk = 0; kk < kl; ++kk) {
      float a[8];
      #pragma unroll
      for (int i=0;i<8;++i) a[i] = shA[(bg*8+i)*LDSB + kk];
      #pragma unroll
      for (int p=0;p<2;++p) {
        const int rr = (vl + p*64)*3;
        const float s0 = shB[(rr+0)*LDSB + kk];
        const float s1 = shB[(rr+1)*LDSB + kk];
        const float s2 = shB[(rr+2)*LDSB + kk];
        #pragma unroll
        for (int i=0;i<8;++i) {
          acc[p][i][0] = fmaf(a[i], s0, acc[p][i][0]);
          acc[p][i][1] = fmaf(a[i], s1, acc[p][i][1]);
          acc[p][i][2] = fmaf(a[i], s2, acc[p][i][2]);
        }
      }
    }
  }

  // epilogue: add template, LBS blend, store
  #pragma unroll
  for (int p=0;p<2;++p) {
    const int v = v0 + vl + p*64;
    if (v >= NV) continue;
    float w5[5];
    #pragma unroll
    for (int j=0;j<5;++j) w5[j] = lbsw[(size_t)v*5 + j];
    const float tx = vtemp[(size_t)v*3+0];
    const float ty = vtemp[(size_t)v*3+1];
    const float tz = vtemp[(size_t)v*3+2];
    #pragma unroll
    for (int i=0;i<8;++i) {
      const int bl = bg*8 + i;
      const float* rl = &sRel[bl*60];
      const float vx = acc[p][i][0]+tx, vy = acc[p][i][1]+ty, vz = acc[p][i][2]+tz;
      float o[3];
      #pragma unroll
      for (int r=0;r<3;++r) {
        float a0=0.f,a1=0.f,a2=0.f,a3=0.f;
        #pragma unroll
        for (int j=0;j<5;++j) {
          a0 = fmaf(w5[j], rl[j*12+r*4+0], a0);
          a1 = fmaf(w5[j], rl[j*12+r*4+1], a1);
          a2 = fmaf(w5[j], rl[j*12+r*4+2], a2);
          a3 = fmaf(w5[j], rl[j*12+r*4+3], a3);
        }
        o[r] = fmaf(a0, vx, fmaf(a1, vy, fmaf(a2, vz, a3)));
      }
      float* dst = vout + ((size_t)(b0+bl)*NV + v)*3;
      dst[0]=o[0]; dst[1]=o[1]; dst[2]=o[2];
    }
  }
}

// ---- k4: landmarks
__launch_bounds__(192)
__global__ void k4_landmarks(const float* __restrict__ verts, const int* __restrict__ faces,
                             const int* __restrict__ lmkf, const float* __restrict__ lmkb,
                             const int* __restrict__ dynf, const float* __restrict__ dynb,
                             const int* __restrict__ fullf, const float* __restrict__ fullb,
                             const int* __restrict__ yidx, float* __restrict__ out2d,
                             float* __restrict__ out3d) {
  const int b = blockIdx.x;
  const int t = threadIdx.x;
  if (t >= 136) return;
  const int which = t >= 68;
  const int i = which ? (t-68) : t;
  int fidx; float bw0,bw1,bw2;
  if (!which) {
    if (i < 17) {
      const int y = yidx[b];
      fidx = dynf[y*17 + i];
      const float* p = dynb + ((size_t)y*17 + i)*3;
      bw0=p[0]; bw1=p[1]; bw2=p[2];
    } else {
      fidx = lmkf[i-17];
      const float* p = lmkb + (size_t)(i-17)*3;
      bw0=p[0]; bw1=p[1]; bw2=p[2];
    }
  } else {
    fidx = fullf[i];
    const float* p = fullb + (size_t)i*3;
    bw0=p[0]; bw1=p[1]; bw2=p[2];
  }
  const int t0 = faces[fidx*3+0], t1 = faces[fidx*3+1], t2 = faces[fidx*3+2];
  const float* vb = verts + (size_t)b*NV*3;
  float* dst = (which ? out3d : out2d) + ((size_t)b*68 + i)*3;
  #pragma unroll
  for (int c=0;c<3;++c)
    dst[c] = vb[(size_t)t0*3+c]*bw0 + vb[(size_t)t1*3+c]*bw1 + vb[(size_t)t2*3+c]*bw2;
}

extern "C" void kernel_launch(void* const* d_in, const int* in_sizes, int n_in,
                              void* d_out, int out_size, void* d_ws, size_t ws_size,
                              hipStream_t stream) {
  const float* shape = (const float*)d_in[0];
  const float* expr  = (const float*)d_in[1];
  const float* pose  = (const float*)d_in[2];
  const float* vtemp = (const float*)d_in[3];
  const float* shdirs= (const float*)d_in[4];
  const float* pdirs = (const float*)d_in[5];
  const float* jreg  = (const float*)d_in[6];
  const float* lbsw  = (const float*)d_in[7];
  const float* neck  = (const float*)d_in[8];
  const float* eye   = (const float*)d_in[9];
  const int*   faces = (const int*)d_in[10];
  const int*   lmkf  = (const int*)d_in[11];
  const float* lmkb  = (const float*)d_in[12];
  const int*   dynf  = (const int*)d_in[13];
  const float* dynb  = (const float*)d_in[14];
  const int*   fullf = (const int*)d_in[15];
  const float* fullb = (const float*)d_in[16];

  float* wsf = (float*)d_ws;
  float* partial = wsf + WS_PARTIAL;
  float* jsd     = wsf + WS_JSD;
  float* Amat    = wsf + WS_AMAT;
  float* reltf   = wsf + WS_RELTF;
  int*   yidx    = (int*)(wsf + WS_Y);

  float* vout  = (float*)d_out;
  float* out2d = vout + (size_t)BATCH*NV*3;
  float* out3d = out2d + (size_t)BATCH*68*3;

  hipLaunchKernelGGL(k1_jsd_partial, dim3(NJ, NCHUNK), dim3(512), 0, stream,
                     jreg, shdirs, vtemp, partial);
  hipLaunchKernelGGL(k1b_jsd_reduce, dim3(9), dim3(256), 0, stream, partial, jsd);
  hipLaunchKernelGGL(k2_pose, dim3(4), dim3(256), 0, stream,
                     shape, expr, pose, neck, eye, jsd, Amat, reltf, yidx);
  hipLaunchKernelGGL(k3_valu, dim3((NV + TV - 1)/TV, BATCH/TB), dim3(512), 0, stream,
                     Amat, shdirs, pdirs, vtemp, lbsw, reltf, vout);
  hipLaunchKernelGGL(k4_landmarks, dim3(BATCH), dim3(192), 0, stream,
                     vout, faces, lmkf, lmkb, dynf, dynb, fullf, fullb, yidx, out2d, out3d);
}